// Round 1
// baseline (5232.663 us; speedup 1.0000x reference)
//
#include <hip/hip_runtime.h>

// LSTM: B=256, T=128, D=64, H=512, 4H=2048, F=256
// Grid: 256 WGs = 16 batch-groups (grp=blockIdx&15, 16 rows each)
//               x 16 hidden-slices (slc=blockIdx>>4, 32 hidden units each)
// Block: 256 threads = 4 waves: kset=wid&1 (16-col halves), kh=wid>>1 (K halves)

#define WH_S 520   // 512 + 8 pad (f16) -> 1040B row stride, 2-way bank alias (free)
#define WX_S 72    // 64 + 8 pad

typedef __attribute__((ext_vector_type(4))) _Float16 f16x4;
typedef __attribute__((ext_vector_type(4))) float    f32x4;

__device__ __forceinline__ float sigm(float x)  { return 1.f / (1.f + __expf(-x)); }
__device__ __forceinline__ float tanhf_(float x){ float e = __expf(2.f * x); return 1.f - 2.f / (e + 1.f); }

__launch_bounds__(256, 1)
__global__ void lstm_persist(const float* __restrict__ obs,
                             const float* __restrict__ Wx,
                             const float* __restrict__ Wh,
                             const float* __restrict__ bvec,
                             _Float16* __restrict__ hbuf,      // [2][256][512] f16
                             unsigned int* __restrict__ bar)   // 16 counters, 64B apart
{
    __shared__ _Float16 sWh[128 * WH_S];   // [col 0..127][K 0..511]; col c: gate=c>>5, u=c&31
    __shared__ _Float16 sWx[128 * WX_S];   // [col][K 0..63]
    __shared__ float    sRed[2048];        // K-split partials: [kset][g][lane][4]

    const int tid  = threadIdx.x;
    const int grp  = blockIdx.x & 15;
    const int slc  = blockIdx.x >> 4;
    const int lane = tid & 63;
    const int wid  = tid >> 6;
    const int kset = wid & 1;
    const int kh   = wid >> 1;
    const int l15  = lane & 15;
    const int l16  = lane >> 4;

    // ---- prologue: stage Wh / Wx slices into LDS as f16 ----
    for (int idx = tid; idx < 512 * 128; idx += 256) {
        int k = idx >> 7, c = idx & 127;
        int gcol = ((c >> 5) << 9) + (slc << 5) + (c & 31);     // gate*512 + slc*32 + u
        sWh[c * WH_S + k] = (_Float16)Wh[k * 2048 + gcol];
    }
    for (int idx = tid; idx < 64 * 128; idx += 256) {
        int k = idx >> 7, c = idx & 127;
        int gcol = ((c >> 5) << 9) + (slc << 5) + (c & 31);
        sWx[c * WX_S + k] = (_Float16)Wx[k * 2048 + gcol];
    }
    __syncthreads();

    const int brow = (grp << 4) + l15;        // A-fragment row (batch)
    const int hloc = (kset << 4) + l15;       // epilogue column within 32-unit slice
    float bia[4];
    #pragma unroll
    for (int g = 0; g < 4; ++g) bia[g] = bvec[(g << 9) + (slc << 5) + hloc];

    float c_reg[4] = {0.f, 0.f, 0.f, 0.f};    // cell state: rows l16*4+rr, col hloc

    for (int t = 0; t < 128; ++t) {
        const _Float16* hcur = hbuf + ((t & 1) ? 131072 : 0);
        _Float16*       hnxt = hbuf + ((t & 1) ? 0 : 131072);

        f32x4 acc[4];
        #pragma unroll
        for (int g = 0; g < 4; ++g) acc[g] = (f32x4){0.f, 0.f, 0.f, 0.f};

        // A fragments: h rows, this wave's K-half (256 wide, 16 MFMA K-steps)
        f16x4 afr[16];
        #pragma unroll
        for (int kk = 0; kk < 16; ++kk) {
            int kbase = ((kh << 4) + kk) << 4;                 // (kh*16+kk)*16
            afr[kk] = *(const f16x4*)(hcur + brow * 512 + kbase + (l16 << 2));
        }
        #pragma unroll
        for (int g = 0; g < 4; ++g) {
            const int c = (g << 5) + (kset << 4) + l15;        // B col in LDS
            const _Float16* wp = &sWh[c * WH_S + (kh << 8) + (l16 << 2)];
            #pragma unroll
            for (int kk = 0; kk < 16; ++kk) {
                f16x4 bf = *(const f16x4*)(wp + (kk << 4));
                acc[g] = __builtin_amdgcn_mfma_f32_16x16x16f16(afr[kk], bf, acc[g], 0, 0, 0);
            }
        }
        if (kh == 1) {                                         // fold in x_t @ Wx
            #pragma unroll
            for (int kx = 0; kx < 4; ++kx) {
                const float* op = obs + ((brow << 7) + t) * 64 + (kx << 4) + (l16 << 2);
                f32x4 ov = *(const f32x4*)op;
                f16x4 af;
                #pragma unroll
                for (int e = 0; e < 4; ++e) af[e] = (_Float16)ov[e];
                #pragma unroll
                for (int g = 0; g < 4; ++g) {
                    const int c = (g << 5) + (kset << 4) + l15;
                    f16x4 bf = *(const f16x4*)(&sWx[c * WX_S + (kx << 4) + (l16 << 2)]);
                    acc[g] = __builtin_amdgcn_mfma_f32_16x16x16f16(af, bf, acc[g], 0, 0, 0);
                }
            }
            #pragma unroll
            for (int g = 0; g < 4; ++g)
                *(f32x4*)(&sRed[(((kset << 2) + g) << 8) + (lane << 2)]) = acc[g];
        }
        __syncthreads();
        if (kh == 0) {                                         // reduce K halves + epilogue
            #pragma unroll
            for (int g = 0; g < 4; ++g)
                acc[g] += *(const f32x4*)(&sRed[(((kset << 2) + g) << 8) + (lane << 2)]);
            #pragma unroll
            for (int rr = 0; rr < 4; ++rr) {
                float iv  = sigm(acc[0][rr] + bia[0]);
                float fv  = sigm(acc[1][rr] + bia[1]);
                float gv  = tanhf_(acc[2][rr] + bia[2]);
                float ovv = sigm(acc[3][rr] + bia[3]);
                float cn  = fv * c_reg[rr] + iv * gv;
                c_reg[rr] = cn;
                float hn  = ovv * tanhf_(cn);
                hnxt[((grp << 4) + (l16 << 2) + rr) * 512 + (slc << 5) + hloc] = (_Float16)hn;
            }
        }
        // ---- group barrier: 16 WGs of this batch-group ----
        __threadfence();
        __syncthreads();
        if (tid == 0) {
            __hip_atomic_fetch_add(bar + (grp << 4), 1u, __ATOMIC_RELEASE, __HIP_MEMORY_SCOPE_AGENT);
            const unsigned tgt = (unsigned)((t + 1) << 4);
            while (__hip_atomic_load(bar + (grp << 4), __ATOMIC_ACQUIRE, __HIP_MEMORY_SCOPE_AGENT) < tgt)
                __builtin_amdgcn_s_sleep(2);
        }
        __syncthreads();
        __threadfence();
    }
}

__launch_bounds__(256)
__global__ void final_proj(const _Float16* __restrict__ hlast,  // [256][512] f16 (hbuf[0])
                           const float* __restrict__ Wd,        // [512][256]
                           const float* __restrict__ bd,        // [256]
                           float* __restrict__ out)             // [256][256]
{
    __shared__ float sh[2048];                                  // 4 rows x 512
    const int tid = threadIdx.x;
    const int rb  = blockIdx.x;                                 // 64 blocks x 4 rows
    for (int idx = tid; idx < 2048; idx += 256)
        sh[idx] = (float)hlast[(rb << 2) * 512 + idx];
    __syncthreads();
    float a0 = 0.f, a1 = 0.f, a2 = 0.f, a3 = 0.f;
    for (int k = 0; k < 512; ++k) {
        float w = Wd[(k << 8) + tid];
        a0 += sh[k] * w; a1 += sh[512 + k] * w; a2 += sh[1024 + k] * w; a3 += sh[1536 + k] * w;
    }
    float bb = bd[tid];
    float v0 = a0 + bb, v1 = a1 + bb, v2 = a2 + bb, v3 = a3 + bb;
    out[((rb << 2) + 0) * 256 + tid] = v0 > 0.f ? v0 : 0.f;
    out[((rb << 2) + 1) * 256 + tid] = v1 > 0.f ? v1 : 0.f;
    out[((rb << 2) + 2) * 256 + tid] = v2 > 0.f ? v2 : 0.f;
    out[((rb << 2) + 3) * 256 + tid] = v3 > 0.f ? v3 : 0.f;
}

extern "C" void kernel_launch(void* const* d_in, const int* in_sizes, int n_in,
                              void* d_out, int out_size, void* d_ws, size_t ws_size,
                              hipStream_t stream)
{
    (void)in_sizes; (void)n_in; (void)out_size; (void)ws_size;
    const float* obs = (const float*)d_in[0];
    const float* Wx  = (const float*)d_in[1];
    const float* Wh  = (const float*)d_in[2];
    const float* bv  = (const float*)d_in[3];
    const float* Wd  = (const float*)d_in[4];
    const float* bd  = (const float*)d_in[5];
    float* out = (float*)d_out;

    _Float16* hbuf    = (_Float16*)d_ws;                          // 2*256*512*2 = 524288 B
    unsigned int* bar = (unsigned int*)((char*)d_ws + 524288);    // 16 x 64B

    hipMemsetAsync(d_ws, 0, 524288 + 1024, stream);               // zero h0 + barrier counters

    void* args[6];
    args[0] = (void*)&obs; args[1] = (void*)&Wx; args[2] = (void*)&Wh;
    args[3] = (void*)&bv;  args[4] = (void*)&hbuf; args[5] = (void*)&bar;
    hipError_t e = hipLaunchCooperativeKernel((const void*)lstm_persist,
                                              dim3(256), dim3(256), args, 0, stream);
    if (e != hipSuccess) {
        // 256 WGs x 1 WG/CU (LDS-limited) co-reside on 256 CUs; plain launch is safe.
        lstm_persist<<<dim3(256), dim3(256), 0, stream>>>(obs, Wx, Wh, bv, hbuf, bar);
    }
    final_proj<<<dim3(64), dim3(256), 0, stream>>>(hbuf, Wd, bd, out);
}

// Round 2
// 683.268 us; speedup vs baseline: 7.6583x; 7.6583x over previous
//
#include <hip/hip_runtime.h>

// LSTM: B=256, T=128, D=64, H=512, 4H=2048, F=256
// Grid: 256 WGs = 16 batch-groups (grp=blockIdx&15, 16 rows each)
//               x 16 hidden-slices (slc=blockIdx>>4, 32 hidden units each)
// Block: 4 waves: kset=wid&1 (16-unit column halves), kh=wid>>1 (K halves).
// MFMA operands SWAPPED vs r1: A = Wh^T (LDS), B = h^T (global, sc1 atomics).
//   D[m=gatecol][n=batch]: lane -> 4 consecutive hidden units, one batch row
//   => h exchange is contiguous u64 relaxed AGENT atomics (IF$-coherent, no fences).

#define WH_S 524   // 512+12 pad: word stride 262 -> bank stride 6 -> <=2-way (free)
#define WX_S 72

typedef __attribute__((ext_vector_type(4))) _Float16 f16x4;
typedef __attribute__((ext_vector_type(4))) float    f32x4;

__device__ __forceinline__ float sigm(float x)  { return 1.f / (1.f + __expf(-x)); }
__device__ __forceinline__ float tanh_(float x) { float e = __expf(2.f * x); return 1.f - 2.f / (e + 1.f); }

__launch_bounds__(256, 1)
__global__ void lstm_persist(const float* __restrict__ obs,
                             const float* __restrict__ Wx,
                             const float* __restrict__ Wh,
                             const float* __restrict__ bvec,
                             unsigned long long* __restrict__ hbuf,  // [2][256][512] f16 viewed as u64
                             unsigned int* __restrict__ bar)         // 16 counters, 64B apart
{
    __shared__ _Float16 sWh[128 * WH_S];   // [col 0..127][K 0..511]; col = gate*32 + u_local
    __shared__ _Float16 sWx[128 * WX_S];
    __shared__ float    sRed[2048];        // K-half partials

    const int tid  = threadIdx.x;
    const int grp  = blockIdx.x & 15;
    const int slc  = blockIdx.x >> 4;
    const int lane = tid & 63;
    const int wid  = tid >> 6;
    const int kset = wid & 1;
    const int kh   = wid >> 1;
    const int l15  = lane & 15;
    const int l16  = lane >> 4;

    // ---- prologue: stage Wh / Wx slices into LDS as f16 ----
    for (int idx = tid; idx < 512 * 128; idx += 256) {
        int k = idx >> 7, c = idx & 127;
        int gcol = ((c >> 5) << 9) + (slc << 5) + (c & 31);
        sWh[c * WH_S + k] = (_Float16)Wh[k * 2048 + gcol];
    }
    for (int idx = tid; idx < 64 * 128; idx += 256) {
        int k = idx >> 7, c = idx & 127;
        int gcol = ((c >> 5) << 9) + (slc << 5) + (c & 31);
        sWx[c * WX_S + k] = (_Float16)Wx[k * 2048 + gcol];
    }
    __syncthreads();

    const int brow  = (grp << 4) + l15;          // batch row this lane supplies/owns
    const int ubase = (kset << 4) + (l16 << 2);  // hidden-unit base within 32-slice (kh0 epilogue)

    f32x4 bia[4];
    #pragma unroll
    for (int g = 0; g < 4; ++g)
        bia[g] = *(const f32x4*)(bvec + (g << 9) + (slc << 5) + ubase);

    float c_reg[4] = {0.f, 0.f, 0.f, 0.f};

    const int hload_base = (brow << 7) + (kh << 6) + l16;                 // u64 index
    const int hstore_idx = (brow << 7) + (slc << 3) + (kset << 2) + l16;  // u64 index

    for (int t = 0; t < 128; ++t) {
        const unsigned long long* hc = hbuf + ((t & 1) ? 32768 : 0);
        unsigned long long*       hn = hbuf + ((t & 1) ? 0 : 32768);

        // obs prefetch (kh==1 waves): B[k=d][n=batch] fragment, 4 consecutive d per lane
        f32x4 ov[4];
        if (kh == 1) {
            const float* op = obs + ((brow << 7) + t) * 64;
            #pragma unroll
            for (int kx = 0; kx < 4; ++kx)
                ov[kx] = *(const f32x4*)(op + (kx << 4) + (l16 << 2));
        }

        // B fragments: h[batch=l15][k], coherent IF$ loads (sc1), no cache maintenance
        f16x4 afr[16];
        #pragma unroll
        for (int kk = 0; kk < 16; ++kk) {
            unsigned long long raw = __hip_atomic_load(hc + hload_base + (kk << 2),
                                                       __ATOMIC_RELAXED, __HIP_MEMORY_SCOPE_AGENT);
            afr[kk] = __builtin_bit_cast(f16x4, raw);
        }

        f32x4 acc[4];
        #pragma unroll
        for (int g = 0; g < 4; ++g) acc[g] = (f32x4){0.f, 0.f, 0.f, 0.f};

        #pragma unroll
        for (int g = 0; g < 4; ++g) {
            const int c = (g << 5) + (kset << 4) + l15;       // A row = gate column
            const _Float16* wp = &sWh[c * WH_S + (kh << 8) + (l16 << 2)];
            #pragma unroll
            for (int kk = 0; kk < 16; ++kk) {
                f16x4 wf = *(const f16x4*)(wp + (kk << 4));
                acc[g] = __builtin_amdgcn_mfma_f32_16x16x16f16(wf, afr[kk], acc[g], 0, 0, 0);
            }
        }
        if (kh == 1) {                                        // fold in x_t @ Wx
            #pragma unroll
            for (int kx = 0; kx < 4; ++kx) {
                f16x4 xf;
                #pragma unroll
                for (int e = 0; e < 4; ++e) xf[e] = (_Float16)ov[kx][e];
                #pragma unroll
                for (int g = 0; g < 4; ++g) {
                    const int c = (g << 5) + (kset << 4) + l15;
                    f16x4 wf = *(const f16x4*)(&sWx[c * WX_S + (kx << 4) + (l16 << 2)]);
                    acc[g] = __builtin_amdgcn_mfma_f32_16x16x16f16(wf, xf, acc[g], 0, 0, 0);
                }
            }
            #pragma unroll
            for (int g = 0; g < 4; ++g)
                *(f32x4*)(&sRed[(((kset << 2) + g) << 8) + (lane << 2)]) = acc[g];
        }
        __syncthreads();
        if (kh == 0) {                                        // reduce K halves + epilogue
            #pragma unroll
            for (int g = 0; g < 4; ++g)
                acc[g] += *(const f32x4*)(&sRed[(((kset << 2) + g) << 8) + (lane << 2)]);
            f16x4 hv;
            #pragma unroll
            for (int rr = 0; rr < 4; ++rr) {                  // acc[g][rr]: gate g, unit ubase+rr, batch brow
                float iv  = sigm (acc[0][rr] + bia[0][rr]);
                float fv  = sigm (acc[1][rr] + bia[1][rr]);
                float gv  = tanh_(acc[2][rr] + bia[2][rr]);
                float ovv = sigm (acc[3][rr] + bia[3][rr]);
                float cn  = fv * c_reg[rr] + iv * gv;
                c_reg[rr] = cn;
                hv[rr] = (_Float16)(ovv * tanh_(cn));
            }
            __hip_atomic_store(hn + hstore_idx, __builtin_bit_cast(unsigned long long, hv),
                               __ATOMIC_RELAXED, __HIP_MEMORY_SCOPE_AGENT);
        }
        // ---- group barrier: all prior sc1 ops drained (vmcnt), then relaxed counter ----
        asm volatile("s_waitcnt vmcnt(0)" ::: "memory");
        __syncthreads();
        if (tid == 0) {
            __hip_atomic_fetch_add(bar + (grp << 4), 1u, __ATOMIC_RELAXED, __HIP_MEMORY_SCOPE_AGENT);
            const unsigned tgt = (unsigned)((t + 1) << 4);
            while (__hip_atomic_load(bar + (grp << 4), __ATOMIC_RELAXED, __HIP_MEMORY_SCOPE_AGENT) < tgt)
                __builtin_amdgcn_s_sleep(1);
        }
        __syncthreads();
    }
}

__launch_bounds__(256)
__global__ void final_proj(const _Float16* __restrict__ hlast,  // [256][512] f16 (hbuf[0])
                           const float* __restrict__ Wd,        // [512][256]
                           const float* __restrict__ bd,        // [256]
                           float* __restrict__ out)             // [256][256]
{
    __shared__ float sh[2048];                                  // 4 rows x 512
    const int tid = threadIdx.x;
    const int rb  = blockIdx.x;
    for (int idx = tid; idx < 2048; idx += 256)
        sh[idx] = (float)hlast[(rb << 2) * 512 + idx];
    __syncthreads();
    float a0 = 0.f, a1 = 0.f, a2 = 0.f, a3 = 0.f;
    for (int k = 0; k < 512; ++k) {
        float w = Wd[(k << 8) + tid];
        a0 += sh[k] * w; a1 += sh[512 + k] * w; a2 += sh[1024 + k] * w; a3 += sh[1536 + k] * w;
    }
    float bb = bd[tid];
    float v0 = a0 + bb, v1 = a1 + bb, v2 = a2 + bb, v3 = a3 + bb;
    out[((rb << 2) + 0) * 256 + tid] = v0 > 0.f ? v0 : 0.f;
    out[((rb << 2) + 1) * 256 + tid] = v1 > 0.f ? v1 : 0.f;
    out[((rb << 2) + 2) * 256 + tid] = v2 > 0.f ? v2 : 0.f;
    out[((rb << 2) + 3) * 256 + tid] = v3 > 0.f ? v3 : 0.f;
}

extern "C" void kernel_launch(void* const* d_in, const int* in_sizes, int n_in,
                              void* d_out, int out_size, void* d_ws, size_t ws_size,
                              hipStream_t stream)
{
    (void)in_sizes; (void)n_in; (void)out_size; (void)ws_size;
    const float* obs = (const float*)d_in[0];
    const float* Wx  = (const float*)d_in[1];
    const float* Wh  = (const float*)d_in[2];
    const float* bv  = (const float*)d_in[3];
    const float* Wd  = (const float*)d_in[4];
    const float* bd  = (const float*)d_in[5];
    float* out = (float*)d_out;

    unsigned long long* hbuf = (unsigned long long*)d_ws;          // 2*256*512*2 = 524288 B
    unsigned int* bar = (unsigned int*)((char*)d_ws + 524288);     // 16 x 64B

    hipMemsetAsync(d_ws, 0, 524288 + 1024, stream);                // zero h0 + barrier counters

    void* args[6];
    args[0] = (void*)&obs; args[1] = (void*)&Wx; args[2] = (void*)&Wh;
    args[3] = (void*)&bv;  args[4] = (void*)&hbuf; args[5] = (void*)&bar;
    hipError_t e = hipLaunchCooperativeKernel((const void*)lstm_persist,
                                              dim3(256), dim3(256), args, 0, stream);
    if (e != hipSuccess) {
        // 256 WGs x 1 WG/CU (LDS-limited) co-reside on 256 CUs; plain launch is safe.
        lstm_persist<<<dim3(256), dim3(256), 0, stream>>>(obs, Wx, Wh, bv, hbuf, bar);
    }
    final_proj<<<dim3(64), dim3(256), 0, stream>>>((const _Float16*)d_ws, Wd, bd, out);
}